// Round 2
// baseline (291.846 us; speedup 1.0000x reference)
//
#include <hip/hip_runtime.h>
#include <hip/hip_bf16.h>

#define HW 16384   // 128*128

typedef unsigned short u16;
typedef unsigned int   u32;
typedef __attribute__((ext_vector_type(8))) short short8v;
typedef __attribute__((ext_vector_type(4))) float float4v;

__device__ __forceinline__ float b2f(u16 v) { return __uint_as_float((u32)v << 16); }
__device__ __forceinline__ u16 f2bf(float f) {   // RNE (cold paths)
  u32 u = __float_as_uint(f);
  u32 r = (u + 0x7fffu + ((u >> 16) & 1u)) >> 16;
  return (u16)r;
}
__device__ __forceinline__ float bflo(u32 u) { return __uint_as_float(u << 16); }
__device__ __forceinline__ float bfhi(u32 u) { return __uint_as_float(u & 0xffff0000u); }
// 1-instruction truncating pack: (hi16(b)<<16)|hi16(a)  [v_perm_b32]
__device__ __forceinline__ u32 pkt(float a, float b) {
  return __builtin_amdgcn_perm(__float_as_uint(b), __float_as_uint(a), 0x07060302u);
}
__device__ __forceinline__ u16 bft(float v) { return (u16)(__float_as_uint(v) >> 16); }  // trunc

// ---------------------------------------------------------------------------
// K0: swizzle ALL weights into MFMA-B fragment order (bf16, RNE).
//  B-frag layout: buf[((ntile*KS + ks)*64 + lane)*8 + j]
//  with o = ntile*16 + (lane&15), k = ks*32 + (lane>>4)*8 + j.
// ---------------------------------------------------------------------------
__global__ __launch_bounds__(256) void k_init(const float* __restrict__ w_dc,
                                              const float* __restrict__ w1,
                                              const float* __restrict__ w_ds,
                                              const float* __restrict__ w3,
                                              const float* __restrict__ w_off,
                                              u16* __restrict__ wTb, u16* __restrict__ wB1,
                                              u16* __restrict__ w3b, u16* __restrict__ woffb) {
  int idx = blockIdx.x * 256 + threadIdx.x;
  if (idx < 147456) {
    int ntile = idx / 18432, r = idx % 18432;
    int ks = r / 512, r2 = r % 512;
    int lane = r2 / 8, j = r2 % 8;
    int o = ntile * 16 + (lane & 15);
    int k = ks * 32 + ((lane >> 4) * 8) + j;
    int tap = k >> 7, ci = k & 127;
    wTb[idx] = f2bf(w_dc[(o * 128 + ci) * 9 + tap]);
  }
  int i1 = idx - 147456;
  if (i1 >= 0 && i1 < 65536) {
    int ntile = i1 / 4096, r = i1 % 4096;
    int ks = r / 512, r2 = r % 512;
    int lane = r2 / 8, j = r2 % 8;
    int o = ntile * 16 + (lane & 15);
    int c = ks * 32 + ((lane >> 4) * 8) + j;
    float v = (ntile < 8) ? w1[o * 256 + c] : w_ds[(o - 128) * 256 + c];
    wB1[i1] = f2bf(v);
  }
  int i2 = idx - 212992;
  if (i2 >= 0 && i2 < 16384) {
    int ntile = i2 / 2048, r = i2 % 2048;
    int ks = r / 512, r2 = r % 512;
    int lane = r2 / 8, j = r2 % 8;
    int o = ntile * 16 + (lane & 15);
    int c = ks * 32 + ((lane >> 4) * 8) + j;
    w3b[i2] = f2bf(w3[o * 128 + c]);
  }
  int i3 = idx - 229376;
  if (i3 >= 0 && i3 < 36864) {
    int ntile = i3 / 18432, r = i3 % 18432;
    int ks = r / 512, r2 = r % 512;
    int lane = r2 / 8, j = r2 % 8;
    int oc = ntile * 16 + (lane & 15);
    int k = ks * 32 + ((lane >> 4) * 8) + j;
    int tap = k >> 7, c = k & 127;
    woffb[i3] = (oc < 27) ? f2bf(w_off[oc * 1152 + c * 9 + tap]) : (u16)0;
  }
}

// ---------------------------------------------------------------------------
// K1: fused conv1+downsample MFMA GEMM. M=32 pos, N=256, K=256.
// grid (4,128,4); block 256 = 4 waves. xA pitch 266 u16 (bank-clean).
// ---------------------------------------------------------------------------
__global__ __launch_bounds__(256) void k_fused1(const float* __restrict__ x,
                                                const u16* __restrict__ wB1,
                                                const float* __restrict__ s1a, const float* __restrict__ t1a,
                                                const float* __restrict__ s1b, const float* __restrict__ t1b,
                                                const float* __restrict__ b_ds,
                                                const float* __restrict__ sd, const float* __restrict__ td,
                                                u16* __restrict__ out1,      // [b][h][w][o]
                                                u16* __restrict__ identb)    // [b][o][h][w]
{
  __shared__ __align__(16) u16 xA[32 * 266];   // [pos][c] bf16, pitch 266
  __shared__ __align__(16) u16 T1[128 * 34];   // [o][pos] transpose buffer
  const int tid = threadIdx.x;
  const int wq = blockIdx.x, h = blockIdx.y, b = blockIdx.z;
  const int wave = tid >> 6, lane = tid & 63;

  {
    const float* xb = x + (size_t)b * 256 * HW + h * 128 + wq * 32;
    u32* dst = (u32*)xA;                 // u32 pitch 133 per pos row
    int cp = tid >> 3, wg = tid & 7;
#pragma unroll
    for (int i = 0; i < 4; ++i) {
      int cpair = i * 32 + cp;           // 0..127
      int c0 = cpair * 2;
      float4 va = *(const float4*)&xb[(size_t)c0 * HW + wg * 4];
      float4 vb = *(const float4*)&xb[(size_t)(c0 + 1) * HW + wg * 4];
      int p0 = wg * 4;
      dst[(p0 + 0) * 133 + cpair] = pkt(va.x, vb.x);
      dst[(p0 + 1) * 133 + cpair] = pkt(va.y, vb.y);
      dst[(p0 + 2) * 133 + cpair] = pkt(va.z, vb.z);
      dst[(p0 + 3) * 133 + cpair] = pkt(va.w, vb.w);
    }
  }
  __syncthreads();

  const int nlo = lane & 15, kgr = lane >> 4;
  float4v acc[2][4];
#pragma unroll
  for (int mt = 0; mt < 2; ++mt)
#pragma unroll
    for (int nt = 0; nt < 4; ++nt) acc[mt][nt] = (float4v)(0.f);

  const u16* a0p = &xA[nlo * 266 + kgr * 8];
  const u16* a1p = &xA[(nlo + 16) * 266 + kgr * 8];
  const u16* bp = &wB1[(((size_t)(wave * 4) * 8) * 64 + lane) * 8];

#pragma unroll
  for (int ks = 0; ks < 8; ++ks) {
    short8v a0 = *(const short8v*)(a0p + ks * 32);
    short8v a1 = *(const short8v*)(a1p + ks * 32);
#pragma unroll
    for (int nt = 0; nt < 4; ++nt) {
      short8v bv = *(const short8v*)(bp + nt * 4096 + ks * 512);
      acc[0][nt] = __builtin_amdgcn_mfma_f32_16x16x32_bf16(a0, bv, acc[0][nt], 0, 0, 0);
      acc[1][nt] = __builtin_amdgcn_mfma_f32_16x16x32_bf16(a1, bv, acc[1][nt], 0, 0, 0);
    }
  }

  const int rbase = kgr * 4;
  if (wave < 2) {
#pragma unroll
    for (int nt = 0; nt < 4; ++nt) {
      int o = (wave * 4 + nt) * 16 + nlo;
      float sa = s1a[o], ta = t1a[o], sb = s1b[o], tb = t1b[o];
#pragma unroll
      for (int mt = 0; mt < 2; ++mt)
#pragma unroll
        for (int r = 0; r < 4; ++r) {
          float v = acc[mt][nt][r];
          v = fmaxf(sa * v + ta, 0.f);
          v = fmaxf(sb * v + tb, 0.f);
          int pos = mt * 16 + rbase + r;
          out1[((size_t)((b * 128 + h) * 128 + wq * 32 + pos)) * 128 + o] = bft(v);
        }
    }
  } else {
#pragma unroll
    for (int nt = 0; nt < 4; ++nt) {
      int og = (wave * 4 + nt) * 16 + nlo - 128;
      float sv = sd[og], tv = td[og], bv = b_ds[og];
#pragma unroll
      for (int mt = 0; mt < 2; ++mt)
#pragma unroll
        for (int r = 0; r < 4; ++r) {
          float v = sv * (acc[mt][nt][r] + bv) + tv;
          T1[og * 34 + mt * 16 + rbase + r] = bft(v);
        }
    }
  }
  __syncthreads();

  {
    int o = tid >> 1, half = tid & 1;
    const u16* src = &T1[o * 34 + half * 16];
    u32 bb[8];
#pragma unroll
    for (int i = 0; i < 8; ++i) bb[i] = *(const u32*)(src + i * 2);
    size_t g = ((size_t)((b * 128 + o) * 128 + h)) * 128 + wq * 32 + half * 16;
    *(uint4*)&identb[g] = make_uint4(bb[0], bb[1], bb[2], bb[3]);
    *(uint4*)&identb[g + 8] = make_uint4(bb[4], bb[5], bb[6], bb[7]);
  }
}

// ---------------------------------------------------------------------------
// K2: MEGA-FUSED DCNv2, v3.
//  Loop A (offset conv): stage the FULL 3x18x128 integer neighborhood once
//    (contiguous coalesced spans of out1), then all 9 taps' MFMAs in ONE
//    phase off shifted LDS rows, K-split over 4 waves (partials in offp).
//    9 tap-phases -> 2 barriers; 2.7x fewer global reads for this part.
//  Loop B (deform conv): 2-tap chunks, double-buffered: 5 phases, 32
//    in-flight corner loads/lane/phase, 16 MFMA/wave/phase.
//  Barriers/block: 21 -> 12. LDS 24.7 KB.
//  grid (8,128,4); block 256 = 4 waves.
// ---------------------------------------------------------------------------
__global__ __launch_bounds__(256, 5) void k_dcn(const u16* __restrict__ out1,
                                                const u16* __restrict__ wTb,
                                                const u16* __restrict__ w3b,
                                                const u16* __restrict__ woffb,
                                                const float* __restrict__ b_off,
                                                const float* __restrict__ b_dc,
                                                const float* __restrict__ s2, const float* __restrict__ t2,
                                                const float* __restrict__ s3a, const float* __restrict__ t3a,
                                                const float* __restrict__ s3b, const float* __restrict__ t3b,
                                                const u16* __restrict__ identb,
                                                float* __restrict__ out) {
  // Union region (17152 B): loopA R = 54 rows x 134 u16 (14472 B);
  // loopB Cbuf = 2 x 32 rows x 134 u16 (17152 B); then P (16x134) + T2.
  __shared__ __align__(16) u16 U[8576];
  __shared__ __align__(16) u32 jobtab[144 * 6];     // 3456 B
  __shared__ __align__(16) float offp[2 * 16 * 32]; // 4096 B  k-split partials

  u16* R  = U;                       // [seg*18+pos][134]
  u16* Cb = U;                       // [(buf*32)+row][134]
  u16* P  = U;                       // [pos][134]
  float* T2 = (float*)(U + 2176);    // byte offset 4352; 128*17*4 = 8704 B

  const int tid = threadIdx.x;
  const int wq = blockIdx.x, h = blockIdx.y, b = blockIdx.z;
  const int wave = tid >> 6, lane = tid & 63;
  const int nlo = lane & 15, kgr = lane >> 4;
  const u16* base = out1 + (size_t)b * HW * 128;
  const int c = lane * 2;
  const int w0 = wq * 16;

  // ---- Phase A1: stage 3x18x128 neighborhood (coalesced contiguous spans) ----
#pragma unroll
  for (int seg = 0; seg < 3; ++seg) {
    int y = h - 1 + seg;
    bool yok = (y >= 0) & (y < 128);
    for (int k = tid; k < 1152; k += 256) {     // 1152 u32 per segment
      int pos = k >> 6, cp = k & 63;
      int x = w0 - 1 + pos;
      u32 v = 0;
      if (yok & (x >= 0) & (x < 128))
        v = *(const u32*)&base[((size_t)(y * 128 + x)) * 128 + cp * 2];
      *(u32*)&R[(seg * 18 + pos) * 134 + cp * 2] = v;
    }
  }
  __syncthreads();

  // ---- Phase A2: offset conv, all 9 taps, K-split across waves ----
  {
    float4v oacc = (float4v)(0.f);
    const int ntile = wave & 1, kg = wave >> 1;
    const int t0 = kg ? 5 : 0, t1 = kg ? 9 : 5;
    for (int t = t0; t < t1; ++t) {
      int ty = t / 3, tx = t % 3;               // 0..2 each
      const u16* ap = &R[(ty * 18 + nlo + tx) * 134 + kgr * 8];
      const u16* bp = &woffb[(((size_t)(ntile * 36 + t * 4)) * 64 + lane) * 8];
#pragma unroll
      for (int ksl = 0; ksl < 4; ++ksl) {
        short8v a = *(const short8v*)(ap + ksl * 32);
        short8v bv = *(const short8v*)(bp + ksl * 512);
        oacc = __builtin_amdgcn_mfma_f32_16x16x32_bf16(a, bv, oacc, 0, 0, 0);
      }
    }
    int oc = ntile * 16 + nlo;
#pragma unroll
    for (int r = 0; r < 4; ++r)
      offp[(kg * 16 + kgr * 4 + r) * 32 + oc] = oacc[r];
  }
  __syncthreads();

  // ---- Phase A3: jobtab (combine k-partials + bias + sigmoid here) ----
  if (tid < 144) {
    int pos = tid / 9, tap = tid % 9;
    int w = w0 + pos;
    float dy  = offp[pos * 32 + tap]      + offp[512 + pos * 32 + tap]      + b_off[tap];
    float dxv = offp[pos * 32 + 9 + tap]  + offp[512 + pos * 32 + 9 + tap]  + b_off[9 + tap];
    float sg  = offp[pos * 32 + 18 + tap] + offp[512 + pos * 32 + 18 + tap] + b_off[18 + tap];
    float mk = 1.f / (1.f + __expf(-sg));
    float py = (float)(h - 1 + tap / 3) + dy;
    float px = (float)(w - 1 + tap % 3) + dxv;
    float fy = floorf(py), fx = floorf(px);
    int y0 = (int)fy, x0 = (int)fx;
    float wy = py - fy, wxf = px - fx;
    bool vy0 = (y0 >= 0) & (y0 < 128), vy1 = (y0 >= -1) & (y0 < 127);
    bool vx0 = (x0 >= 0) & (x0 < 128), vx1 = (x0 >= -1) & (x0 < 127);
    float w00 = (vy0 & vx0) ? (1.f - wy) * (1.f - wxf) * mk : 0.f;
    float w01 = (vy0 & vx1) ? (1.f - wy) * wxf * mk : 0.f;
    float w10 = (vy1 & vx0) ? wy * (1.f - wxf) * mk : 0.f;
    float w11 = (vy1 & vx1) ? wy * wxf * mk : 0.f;
    int y0c = min(max(y0, 0), 127), y1c = min(max(y0 + 1, 0), 127);
    int x0c = min(max(x0, 0), 127), x1c = min(max(x0 + 1, 0), 127);
    u32* jt = &jobtab[tid * 6];
    jt[0] = (u32)((y0c * 128 + x0c) * 128);
    jt[1] = (u32)((x1c - x0c) * 128) | ((u32)((y1c - y0c) * 16384) << 16);
    ((float*)jt)[2] = w00; ((float*)jt)[3] = w01;
    ((float*)jt)[4] = w10; ((float*)jt)[5] = w11;
  }
  __syncthreads();

  // ---- Loop B: DCN conv, 2-tap chunks (taps {2c,2c+1}), double-buffered ----
  float4v acc[2];
  acc[0] = (float4v)(0.f); acc[1] = (float4v)(0.f);

  // prologue: stage chunk 0 (taps 0,1) -> buf0. job j: tap=j>>4, pos=j&15.
  {
    u32 vP[8][4];
#pragma unroll
    for (int i = 0; i < 8; ++i) {
      int j = wave * 8 + i;
      const u32* jt = &jobtab[((j & 15) * 9 + (j >> 4)) * 6];
      u32 a0 = jt[0], st = jt[1];
      const u16* p = base + a0 + c;
      int dx = (int)(st & 0xffffu), dyy = (int)(st >> 16);
      vP[i][0] = *(const u32*)p;
      vP[i][1] = *(const u32*)(p + dx);
      vP[i][2] = *(const u32*)(p + dyy);
      vP[i][3] = *(const u32*)(p + dyy + dx);
    }
#pragma unroll
    for (int i = 0; i < 8; ++i) {
      int j = wave * 8 + i;
      const u32* jt = &jobtab[((j & 15) * 9 + (j >> 4)) * 6];
      float w00 = ((const float*)jt)[2], w01 = ((const float*)jt)[3];
      float w10 = ((const float*)jt)[4], w11 = ((const float*)jt)[5];
      float lo = w00 * bflo(vP[i][0]) + w01 * bflo(vP[i][1]) + w10 * bflo(vP[i][2]) + w11 * bflo(vP[i][3]);
      float hi = w00 * bfhi(vP[i][0]) + w01 * bfhi(vP[i][1]) + w10 * bfhi(vP[i][2]) + w11 * bfhi(vP[i][3]);
      *(u32*)&Cb[((j >> 4) * 16 + (j & 15)) * 134 + c] = pkt(lo, hi);
    }
  }
  __syncthreads();

  for (int ch = 0; ch < 5; ++ch) {
    const int cur = ch & 1, nxt = cur ^ 1;
    u32 vB[8][4];
    if (ch < 4) {        // issue corner loads for chunk ch+1
#pragma unroll
      for (int i = 0; i < 8; ++i) {
        int j = wave * 8 + i;
        int tap = 2 * (ch + 1) + (j >> 4);
        if (tap < 9) {
          const u32* jt = &jobtab[((j & 15) * 9 + tap) * 6];
          u32 a0 = jt[0], st = jt[1];
          const u16* p = base + a0 + c;
          int dx = (int)(st & 0xffffu), dyy = (int)(st >> 16);
          vB[i][0] = *(const u32*)p;
          vB[i][1] = *(const u32*)(p + dx);
          vB[i][2] = *(const u32*)(p + dyy);
          vB[i][3] = *(const u32*)(p + dyy + dx);
        }
      }
    }
    // MFMA on chunk ch (up to 2 taps x 4 kslices x 2 ntiles)
#pragma unroll
    for (int th = 0; th < 2; ++th) {
      int tap = 2 * ch + th;
      if (ch < 4 || th == 0) {
        const u16* ap = &Cb[(cur * 32 + th * 16 + nlo) * 134 + kgr * 8];
        const u16* b0p = &wTb[(((size_t)((wave * 2 + 0) * 36 + tap * 4)) * 64 + lane) * 8];
        const u16* b1p = &wTb[(((size_t)((wave * 2 + 1) * 36 + tap * 4)) * 64 + lane) * 8];
#pragma unroll
        for (int ksl = 0; ksl < 4; ++ksl) {
          short8v a = *(const short8v*)(ap + ksl * 32);
          short8v b0 = *(const short8v*)(b0p + ksl * 512);
          short8v b1 = *(const short8v*)(b1p + ksl * 512);
          acc[0] = __builtin_amdgcn_mfma_f32_16x16x32_bf16(a, b0, acc[0], 0, 0, 0);
          acc[1] = __builtin_amdgcn_mfma_f32_16x16x32_bf16(a, b1, acc[1], 0, 0, 0);
        }
      }
    }
    // blend + write chunk ch+1
    if (ch < 4) {
#pragma unroll
      for (int i = 0; i < 8; ++i) {
        int j = wave * 8 + i;
        int tap = 2 * (ch + 1) + (j >> 4);
        if (tap < 9) {
          const u32* jt = &jobtab[((j & 15) * 9 + tap) * 6];
          float w00 = ((const float*)jt)[2], w01 = ((const float*)jt)[3];
          float w10 = ((const float*)jt)[4], w11 = ((const float*)jt)[5];
          float lo = w00 * bflo(vB[i][0]) + w01 * bflo(vB[i][1]) + w10 * bflo(vB[i][2]) + w11 * bflo(vB[i][3]);
          float hi = w00 * bfhi(vB[i][0]) + w01 * bfhi(vB[i][1]) + w10 * bfhi(vB[i][2]) + w11 * bfhi(vB[i][3]);
          *(u32*)&Cb[(nxt * 32 + (j >> 4) * 16 + (j & 15)) * 134 + c] = pkt(lo, hi);
        }
      }
    }
    __syncthreads();
  }

  // ---- bn2 + relu -> P[pos][o] bf16 (overlays Cb; loop-B final barrier covers) ----
  const int rbase = kgr * 4;
#pragma unroll
  for (int nt = 0; nt < 2; ++nt) {
    int o = (wave * 2 + nt) * 16 + nlo;
    float bd = b_dc[o], ss = s2[o], tt = t2[o];
#pragma unroll
    for (int r = 0; r < 4; ++r) {
      float v = acc[nt][r] + bd;
      v = fmaxf(ss * v + tt, 0.f);
      P[(rbase + r) * 134 + o] = bft(v);
    }
  }
  __syncthreads();

  // ---- conv3 MFMA (M=16, K=128) from P ----
  float4v acc2[2];
  acc2[0] = (float4v)(0.f); acc2[1] = (float4v)(0.f);
  {
    const u16* b0p = &w3b[(((size_t)(wave * 2 + 0) * 4) * 64 + lane) * 8];
    const u16* b1p = &w3b[(((size_t)(wave * 2 + 1) * 4) * 64 + lane) * 8];
#pragma unroll
    for (int ks = 0; ks < 4; ++ks) {
      short8v a = *(const short8v*)&P[nlo * 134 + ks * 32 + kgr * 8];
      short8v b0 = *(const short8v*)(b0p + ks * 512);
      short8v b1 = *(const short8v*)(b1p + ks * 512);
      acc2[0] = __builtin_amdgcn_mfma_f32_16x16x32_bf16(a, b0, acc2[0], 0, 0, 0);
      acc2[1] = __builtin_amdgcn_mfma_f32_16x16x32_bf16(a, b1, acc2[1], 0, 0, 0);
    }
  }

  // bn3 chain -> T2[o][pos] (disjoint from P region; no barrier needed)
#pragma unroll
  for (int nt = 0; nt < 2; ++nt) {
    int o = (wave * 2 + nt) * 16 + nlo;
    float sa = s3a[o], ta = t3a[o], sb = s3b[o], tb = t3b[o];
#pragma unroll
    for (int r = 0; r < 4; ++r) {
      float v = acc2[nt][r];
      v = fmaxf(sa * v + ta, 0.f);
      v = sb * v + tb;
      T2[o * 17 + rbase + r] = v;
    }
  }
  __syncthreads();

  // ---- transpose + ident + relu -> out NCHW fp32 ----
  {
    int o = tid >> 1, half = tid & 1;
    size_t g = ((size_t)((b * 128 + o) * 128 + h)) * 128 + wq * 16 + half * 8;
    const float* trow = &T2[o * 17 + half * 8];
    uint4 iv = *(const uint4*)&identb[g];
    u32 iw[4] = {iv.x, iv.y, iv.z, iv.w};
    float4 ov[2];
#pragma unroll
    for (int q = 0; q < 2; ++q) {
      float r0 = trow[q * 4 + 0] + bflo(iw[q * 2]);
      float r1 = trow[q * 4 + 1] + bfhi(iw[q * 2]);
      float r2 = trow[q * 4 + 2] + bflo(iw[q * 2 + 1]);
      float r3 = trow[q * 4 + 3] + bfhi(iw[q * 2 + 1]);
      ov[q] = make_float4(fmaxf(r0, 0.f), fmaxf(r1, 0.f), fmaxf(r2, 0.f), fmaxf(r3, 0.f));
    }
    *(float4*)&out[g] = ov[0];
    *(float4*)&out[g + 4] = ov[1];
  }
}

// ---------------------------------------------------------------------------
extern "C" void kernel_launch(void* const* d_in, const int* in_sizes, int n_in,
                              void* d_out, int out_size, void* d_ws, size_t ws_size,
                              hipStream_t stream) {
  const float* x     = (const float*)d_in[0];
  const float* w1    = (const float*)d_in[1];
  const float* s1a   = (const float*)d_in[2];
  const float* t1a   = (const float*)d_in[3];
  const float* s1b   = (const float*)d_in[4];
  const float* t1b   = (const float*)d_in[5];
  const float* w_off = (const float*)d_in[6];
  const float* b_off = (const float*)d_in[7];
  const float* w_dc  = (const float*)d_in[8];
  const float* b_dc  = (const float*)d_in[9];
  const float* s2    = (const float*)d_in[10];
  const float* t2    = (const float*)d_in[11];
  const float* w3    = (const float*)d_in[12];
  const float* s3a   = (const float*)d_in[13];
  const float* t3a   = (const float*)d_in[14];
  const float* s3b   = (const float*)d_in[15];
  const float* t3b   = (const float*)d_in[16];
  const float* w_ds  = (const float*)d_in[17];
  const float* b_ds  = (const float*)d_in[18];
  const float* sd    = (const float*)d_in[19];
  const float* td    = (const float*)d_in[20];

  char* ws = (char*)d_ws;
  u16* wTb    = (u16*)(ws + 0);            //    294,912 B
  u16* wB1    = (u16*)(ws + 294912);       //    131,072 B
  u16* w3b    = (u16*)(ws + 425984);       //     32,768 B
  u16* woffb  = (u16*)(ws + 458752);       //     73,728 B
  u16* out1   = (u16*)(ws + 532480);       // 16,777,216 B  NHWC bf16
  u16* identb = (u16*)(ws + 17309696);     // 16,777,216 B  NCHW bf16

  k_init  <<<1040, 256, 0, stream>>>(w_dc, w1, w_ds, w3, w_off, wTb, wB1, w3b, woffb);
  k_fused1<<<dim3(4, 128, 4), 256, 0, stream>>>(x, wB1, s1a, t1a, s1b, t1b, b_ds, sd, td, out1, identb);
  k_dcn   <<<dim3(8, 128, 4), 256, 0, stream>>>(out1, wTb, w3b, woffb, b_off, b_dc, s2, t2,
                                                s3a, t3a, s3b, t3b, identb, (float*)d_out);
}

// Round 3
// 287.616 us; speedup vs baseline: 1.0147x; 1.0147x over previous
//
#include <hip/hip_runtime.h>
#include <hip/hip_bf16.h>

#define HW 16384   // 128*128

typedef unsigned short u16;
typedef unsigned int   u32;
typedef __attribute__((ext_vector_type(8))) short short8v;
typedef __attribute__((ext_vector_type(4))) float float4v;

__device__ __forceinline__ float b2f(u16 v) { return __uint_as_float((u32)v << 16); }
__device__ __forceinline__ u16 f2bf(float f) {   // RNE (cold paths)
  u32 u = __float_as_uint(f);
  u32 r = (u + 0x7fffu + ((u >> 16) & 1u)) >> 16;
  return (u16)r;
}
__device__ __forceinline__ float bflo(u32 u) { return __uint_as_float(u << 16); }
__device__ __forceinline__ float bfhi(u32 u) { return __uint_as_float(u & 0xffff0000u); }
// 1-instruction truncating pack: (hi16(b)<<16)|hi16(a)  [v_perm_b32]
__device__ __forceinline__ u32 pkt(float a, float b) {
  return __builtin_amdgcn_perm(__float_as_uint(b), __float_as_uint(a), 0x07060302u);
}
__device__ __forceinline__ u16 bft(float v) { return (u16)(__float_as_uint(v) >> 16); }  // trunc

// ---------------------------------------------------------------------------
// K0: swizzle ALL weights into MFMA-B fragment order (bf16, RNE).
//  B-frag layout: buf[((ntile*KS + ks)*64 + lane)*8 + j]
//  with o = ntile*16 + (lane&15), k = ks*32 + (lane>>4)*8 + j.
// ---------------------------------------------------------------------------
__global__ __launch_bounds__(256) void k_init(const float* __restrict__ w_dc,
                                              const float* __restrict__ w1,
                                              const float* __restrict__ w_ds,
                                              const float* __restrict__ w3,
                                              const float* __restrict__ w_off,
                                              u16* __restrict__ wTb, u16* __restrict__ wB1,
                                              u16* __restrict__ w3b, u16* __restrict__ woffb) {
  int idx = blockIdx.x * 256 + threadIdx.x;
  if (idx < 147456) {
    int ntile = idx / 18432, r = idx % 18432;
    int ks = r / 512, r2 = r % 512;
    int lane = r2 / 8, j = r2 % 8;
    int o = ntile * 16 + (lane & 15);
    int k = ks * 32 + ((lane >> 4) * 8) + j;
    int tap = k >> 7, ci = k & 127;
    wTb[idx] = f2bf(w_dc[(o * 128 + ci) * 9 + tap]);
  }
  int i1 = idx - 147456;
  if (i1 >= 0 && i1 < 65536) {
    int ntile = i1 / 4096, r = i1 % 4096;
    int ks = r / 512, r2 = r % 512;
    int lane = r2 / 8, j = r2 % 8;
    int o = ntile * 16 + (lane & 15);
    int c = ks * 32 + ((lane >> 4) * 8) + j;
    float v = (ntile < 8) ? w1[o * 256 + c] : w_ds[(o - 128) * 256 + c];
    wB1[i1] = f2bf(v);
  }
  int i2 = idx - 212992;
  if (i2 >= 0 && i2 < 16384) {
    int ntile = i2 / 2048, r = i2 % 2048;
    int ks = r / 512, r2 = r % 512;
    int lane = r2 / 8, j = r2 % 8;
    int o = ntile * 16 + (lane & 15);
    int c = ks * 32 + ((lane >> 4) * 8) + j;
    w3b[i2] = f2bf(w3[o * 128 + c]);
  }
  int i3 = idx - 229376;
  if (i3 >= 0 && i3 < 36864) {
    int ntile = i3 / 18432, r = i3 % 18432;
    int ks = r / 512, r2 = r % 512;
    int lane = r2 / 8, j = r2 % 8;
    int oc = ntile * 16 + (lane & 15);
    int k = ks * 32 + ((lane >> 4) * 8) + j;
    int tap = k >> 7, c = k & 127;
    woffb[i3] = (oc < 27) ? f2bf(w_off[oc * 1152 + c * 9 + tap]) : (u16)0;
  }
}

// ---------------------------------------------------------------------------
// K1: fused conv1+downsample MFMA GEMM. M=32 pos, N=256, K=256.
// grid (4,128,4); block 256 = 4 waves. xA pitch 266 u16 (bank-clean).
// ---------------------------------------------------------------------------
__global__ __launch_bounds__(256) void k_fused1(const float* __restrict__ x,
                                                const u16* __restrict__ wB1,
                                                const float* __restrict__ s1a, const float* __restrict__ t1a,
                                                const float* __restrict__ s1b, const float* __restrict__ t1b,
                                                const float* __restrict__ b_ds,
                                                const float* __restrict__ sd, const float* __restrict__ td,
                                                u16* __restrict__ out1,      // [b][h][w][o]
                                                u16* __restrict__ identb)    // [b][o][h][w]
{
  __shared__ __align__(16) u16 xA[32 * 266];   // [pos][c] bf16, pitch 266
  __shared__ __align__(16) u16 T1[128 * 34];   // [o][pos] transpose buffer
  const int tid = threadIdx.x;
  const int wq = blockIdx.x, h = blockIdx.y, b = blockIdx.z;
  const int wave = tid >> 6, lane = tid & 63;

  {
    const float* xb = x + (size_t)b * 256 * HW + h * 128 + wq * 32;
    u32* dst = (u32*)xA;                 // u32 pitch 133 per pos row
    int cp = tid >> 3, wg = tid & 7;
#pragma unroll
    for (int i = 0; i < 4; ++i) {
      int cpair = i * 32 + cp;           // 0..127
      int c0 = cpair * 2;
      float4 va = *(const float4*)&xb[(size_t)c0 * HW + wg * 4];
      float4 vb = *(const float4*)&xb[(size_t)(c0 + 1) * HW + wg * 4];
      int p0 = wg * 4;
      dst[(p0 + 0) * 133 + cpair] = pkt(va.x, vb.x);
      dst[(p0 + 1) * 133 + cpair] = pkt(va.y, vb.y);
      dst[(p0 + 2) * 133 + cpair] = pkt(va.z, vb.z);
      dst[(p0 + 3) * 133 + cpair] = pkt(va.w, vb.w);
    }
  }
  __syncthreads();

  const int nlo = lane & 15, kgr = lane >> 4;
  float4v acc[2][4];
#pragma unroll
  for (int mt = 0; mt < 2; ++mt)
#pragma unroll
    for (int nt = 0; nt < 4; ++nt) acc[mt][nt] = (float4v)(0.f);

  const u16* a0p = &xA[nlo * 266 + kgr * 8];
  const u16* a1p = &xA[(nlo + 16) * 266 + kgr * 8];
  const u16* bp = &wB1[(((size_t)(wave * 4) * 8) * 64 + lane) * 8];

#pragma unroll
  for (int ks = 0; ks < 8; ++ks) {
    short8v a0 = *(const short8v*)(a0p + ks * 32);
    short8v a1 = *(const short8v*)(a1p + ks * 32);
#pragma unroll
    for (int nt = 0; nt < 4; ++nt) {
      short8v bv = *(const short8v*)(bp + nt * 4096 + ks * 512);
      acc[0][nt] = __builtin_amdgcn_mfma_f32_16x16x32_bf16(a0, bv, acc[0][nt], 0, 0, 0);
      acc[1][nt] = __builtin_amdgcn_mfma_f32_16x16x32_bf16(a1, bv, acc[1][nt], 0, 0, 0);
    }
  }

  const int rbase = kgr * 4;
  if (wave < 2) {
#pragma unroll
    for (int nt = 0; nt < 4; ++nt) {
      int o = (wave * 4 + nt) * 16 + nlo;
      float sa = s1a[o], ta = t1a[o], sb = s1b[o], tb = t1b[o];
#pragma unroll
      for (int mt = 0; mt < 2; ++mt)
#pragma unroll
        for (int r = 0; r < 4; ++r) {
          float v = acc[mt][nt][r];
          v = fmaxf(sa * v + ta, 0.f);
          v = fmaxf(sb * v + tb, 0.f);
          int pos = mt * 16 + rbase + r;
          out1[((size_t)((b * 128 + h) * 128 + wq * 32 + pos)) * 128 + o] = bft(v);
        }
    }
  } else {
#pragma unroll
    for (int nt = 0; nt < 4; ++nt) {
      int og = (wave * 4 + nt) * 16 + nlo - 128;
      float sv = sd[og], tv = td[og], bv = b_ds[og];
#pragma unroll
      for (int mt = 0; mt < 2; ++mt)
#pragma unroll
        for (int r = 0; r < 4; ++r) {
          float v = sv * (acc[mt][nt][r] + bv) + tv;
          T1[og * 34 + mt * 16 + rbase + r] = bft(v);
        }
    }
  }
  __syncthreads();

  {
    int o = tid >> 1, half = tid & 1;
    const u16* src = &T1[o * 34 + half * 16];
    u32 bb[8];
#pragma unroll
    for (int i = 0; i < 8; ++i) bb[i] = *(const u32*)(src + i * 2);
    size_t g = ((size_t)((b * 128 + o) * 128 + h)) * 128 + wq * 32 + half * 16;
    *(uint4*)&identb[g] = make_uint4(bb[0], bb[1], bb[2], bb[3]);
    *(uint4*)&identb[g + 8] = make_uint4(bb[4], bb[5], bb[6], bb[7]);
  }
}

// ---------------------------------------------------------------------------
// K2: MEGA-FUSED DCNv2, v4 — deep-pipelined loop B.
//  Loop A: one-shot 3x18x128 neighborhood staging + 9-tap offset conv
//    K-split over 4 waves (unchanged from v3; saves redundant fetch).
//  Loop B: 1-tap chunks with 2-DEEP REGISTER PREFETCH across RAW barriers:
//    phase t = { bfrag loads(t) ; issue gathers(t+2)->regs ; MFMA(t) ;
//                blend(t+1)->LDS ; lgkmcnt(0) ; s_barrier }.
//    Gathers stay in flight across barriers (no vmcnt(0) drain — registers
//    are private). Jobtab packed at stride 8 dw (b64 addr + b128 weights);
//    gather bases scalarized via readfirstlane (saddr-form loads).
//  grid (8,128,4); block 256 = 4 waves. LDS ~22.6 KB.
// ---------------------------------------------------------------------------
__global__ __launch_bounds__(256) void k_dcn(const u16* __restrict__ out1,
                                             const u16* __restrict__ wTb,
                                             const u16* __restrict__ w3b,
                                             const u16* __restrict__ woffb,
                                             const float* __restrict__ b_off,
                                             const float* __restrict__ b_dc,
                                             const float* __restrict__ s2, const float* __restrict__ t2,
                                             const float* __restrict__ s3a, const float* __restrict__ t3a,
                                             const float* __restrict__ s3b, const float* __restrict__ t3b,
                                             const u16* __restrict__ identb,
                                             float* __restrict__ out) {
  // U overlays: loopA R = 54x134 u16 (14472 B) ; loopB Ab dbuf = 2x16x134 u16
  // (8576 B) ; then P (16x134 u16) + T2 (float, byte offset 4352, 8704 B).
  __shared__ __align__(16) u16 U[7240];             // 14480 B
  __shared__ __align__(16) u32 jobtab[144 * 8];     //  4608 B (stride 8 dw)
  __shared__ __align__(16) float offp[2 * 16 * 32]; //  4096 B k-split partials

  u16* R  = U;                       // [seg*18+pos][134]
  u16* P  = U;                       // [pos][134]
  float* T2 = (float*)(U + 2176);    // byte offset 4352; 128*17*4 = 8704 B

  const int tid = threadIdx.x;
  const int wq = blockIdx.x, h = blockIdx.y, b = blockIdx.z;
  const int wave = tid >> 6, lane = tid & 63;
  const int nlo = lane & 15, kgr = lane >> 4;
  const u16* base = out1 + (size_t)b * HW * 128;
  const int c = lane * 2;
  const int w0 = wq * 16;

  // ---- Phase A1: stage 3x18x128 neighborhood (coalesced contiguous spans) ----
#pragma unroll
  for (int seg = 0; seg < 3; ++seg) {
    int y = h - 1 + seg;
    bool yok = (y >= 0) & (y < 128);
    for (int k = tid; k < 1152; k += 256) {     // 1152 u32 per segment
      int pos = k >> 6, cp = k & 63;
      int x = w0 - 1 + pos;
      u32 v = 0;
      if (yok & (x >= 0) & (x < 128))
        v = *(const u32*)&base[((size_t)(y * 128 + x)) * 128 + cp * 2];
      *(u32*)&R[(seg * 18 + pos) * 134 + cp * 2] = v;
    }
  }
  __syncthreads();

  // ---- Phase A2: offset conv, all 9 taps, K-split across waves ----
  {
    float4v oacc = (float4v)(0.f);
    const int ntile = wave & 1, kg = wave >> 1;
    const int t0 = kg ? 5 : 0, t1 = kg ? 9 : 5;
    for (int t = t0; t < t1; ++t) {
      int ty = t / 3, tx = t % 3;               // 0..2 each
      const u16* ap = &R[(ty * 18 + nlo + tx) * 134 + kgr * 8];
      const u16* bp = &woffb[(((size_t)(ntile * 36 + t * 4)) * 64 + lane) * 8];
#pragma unroll
      for (int ksl = 0; ksl < 4; ++ksl) {
        short8v a = *(const short8v*)(ap + ksl * 32);
        short8v bv = *(const short8v*)(bp + ksl * 512);
        oacc = __builtin_amdgcn_mfma_f32_16x16x32_bf16(a, bv, oacc, 0, 0, 0);
      }
    }
    int oc = ntile * 16 + nlo;
#pragma unroll
    for (int r = 0; r < 4; ++r)
      offp[(kg * 16 + kgr * 4 + r) * 32 + oc] = oacc[r];
  }
  __syncthreads();

  // ---- Phase A3: jobtab (combine k-partials + bias + sigmoid) ----
  if (tid < 144) {
    int pos = tid / 9, tap = tid % 9;
    int w = w0 + pos;
    float dy  = offp[pos * 32 + tap]      + offp[512 + pos * 32 + tap]      + b_off[tap];
    float dxv = offp[pos * 32 + 9 + tap]  + offp[512 + pos * 32 + 9 + tap]  + b_off[9 + tap];
    float sg  = offp[pos * 32 + 18 + tap] + offp[512 + pos * 32 + 18 + tap] + b_off[18 + tap];
    float mk = 1.f / (1.f + __expf(-sg));
    float py = (float)(h - 1 + tap / 3) + dy;
    float px = (float)(w - 1 + tap % 3) + dxv;
    float fy = floorf(py), fx = floorf(px);
    int y0 = (int)fy, x0 = (int)fx;
    float wy = py - fy, wxf = px - fx;
    bool vy0 = (y0 >= 0) & (y0 < 128), vy1 = (y0 >= -1) & (y0 < 127);
    bool vx0 = (x0 >= 0) & (x0 < 128), vx1 = (x0 >= -1) & (x0 < 127);
    float w00 = (vy0 & vx0) ? (1.f - wy) * (1.f - wxf) * mk : 0.f;
    float w01 = (vy0 & vx1) ? (1.f - wy) * wxf * mk : 0.f;
    float w10 = (vy1 & vx0) ? wy * (1.f - wxf) * mk : 0.f;
    float w11 = (vy1 & vx1) ? wy * wxf * mk : 0.f;
    int y0c = min(max(y0, 0), 127), y1c = min(max(y0 + 1, 0), 127);
    int x0c = min(max(x0, 0), 127), x1c = min(max(x0 + 1, 0), 127);
    u32* jt = &jobtab[tid * 8];
    jt[0] = (u32)((y0c * 128 + x0c) * 128);
    jt[1] = (u32)((x1c - x0c) * 128) | ((u32)((y1c - y0c) * 16384) << 16);
    ((float*)jt)[4] = w00; ((float*)jt)[5] = w01;
    ((float*)jt)[6] = w10; ((float*)jt)[7] = w11;
  }
  __syncthreads();

  // ---- Loop B: 1-tap chunks, 2-deep register prefetch, raw barriers ----
  float4v acc[2];
  acc[0] = (float4v)(0.f); acc[1] = (float4v)(0.f);
  u32 vr0[4][4], vr1[4][4];

  // gather issue: wave-uniform bases scalarized; saddr-form loads
  auto ISSUE = [&](int t, u32 (&vr)[4][4]) {
#pragma unroll
    for (int i = 0; i < 4; ++i) {
      int pos = wave * 4 + i;
      const u32* jt = &jobtab[(pos * 9 + t) * 8];
      u32 a0 = (u32)__builtin_amdgcn_readfirstlane((int)jt[0]);
      u32 st = (u32)__builtin_amdgcn_readfirstlane((int)jt[1]);
      const u16* p = base + a0;
      int dx = (int)(st & 0xffffu), dyy = (int)(st >> 16);
      vr[i][0] = *(const u32*)(p + c);
      vr[i][1] = *(const u32*)(p + dx + c);
      vr[i][2] = *(const u32*)(p + dyy + c);
      vr[i][3] = *(const u32*)(p + dyy + dx + c);
    }
  };
  auto BLEND = [&](int t, u32 (&vr)[4][4], int buf) {
#pragma unroll
    for (int i = 0; i < 4; ++i) {
      int pos = wave * 4 + i;
      float4 w = *(const float4*)&jobtab[(pos * 9 + t) * 8 + 4];
      float lo = w.x * bflo(vr[i][0]) + w.y * bflo(vr[i][1])
               + w.z * bflo(vr[i][2]) + w.w * bflo(vr[i][3]);
      float hi = w.x * bfhi(vr[i][0]) + w.y * bfhi(vr[i][1])
               + w.z * bfhi(vr[i][2]) + w.w * bfhi(vr[i][3]);
      *(u32*)&U[buf * 2144 + pos * 134 + c] = pkt(lo, hi);
    }
  };

  // prologue: L(0), L(1) in flight; blend(0) -> Ab[0]
  ISSUE(0, vr0);
  ISSUE(1, vr1);
  BLEND(0, vr0, 0);
  __builtin_amdgcn_sched_barrier(0);
  asm volatile("s_waitcnt lgkmcnt(0)" ::: "memory");
  __builtin_amdgcn_s_barrier();
  __builtin_amdgcn_sched_barrier(0);

#pragma unroll
  for (int t = 0; t < 9; ++t) {
    // B-fragments for tap t FIRST (so MFMA's vmcnt wait never drains gathers)
    short8v bf0[4], bf1[4];
    {
      const u16* b0p = &wTb[(((size_t)((wave * 2 + 0) * 36 + t * 4)) * 64 + lane) * 8];
      const u16* b1p = &wTb[(((size_t)((wave * 2 + 1) * 36 + t * 4)) * 64 + lane) * 8];
#pragma unroll
      for (int ksl = 0; ksl < 4; ++ksl) {
        bf0[ksl] = *(const short8v*)(b0p + ksl * 512);
        bf1[ksl] = *(const short8v*)(b1p + ksl * 512);
      }
    }
    // issue gathers for tap t+2 into the register set freed by blend(t)
    if (t <= 6) {
      if (t & 1) ISSUE(t + 2, vr1); else ISSUE(t + 2, vr0);
    }
    // MFMA on tap t from Ab[t&1]
    {
      const u16* ap = &U[(t & 1) * 2144 + nlo * 134 + kgr * 8];
#pragma unroll
      for (int ksl = 0; ksl < 4; ++ksl) {
        short8v a = *(const short8v*)(ap + ksl * 32);
        acc[0] = __builtin_amdgcn_mfma_f32_16x16x32_bf16(a, bf0[ksl], acc[0], 0, 0, 0);
        acc[1] = __builtin_amdgcn_mfma_f32_16x16x32_bf16(a, bf1[ksl], acc[1], 0, 0, 0);
      }
    }
    // blend tap t+1 -> Ab[(t+1)&1]
    if (t <= 7) {
      if (t & 1) BLEND(t + 1, vr0, (t + 1) & 1);
      else       BLEND(t + 1, vr1, (t + 1) & 1);
    }
    __builtin_amdgcn_sched_barrier(0);
    asm volatile("s_waitcnt lgkmcnt(0)" ::: "memory");
    __builtin_amdgcn_s_barrier();
    __builtin_amdgcn_sched_barrier(0);
  }

  // ---- bn2 + relu -> P[pos][o] bf16 (overlays Ab[0]; loop's barrier covers) ----
  const int rbase = kgr * 4;
#pragma unroll
  for (int nt = 0; nt < 2; ++nt) {
    int o = (wave * 2 + nt) * 16 + nlo;
    float bd = b_dc[o], ss = s2[o], tt = t2[o];
#pragma unroll
    for (int r = 0; r < 4; ++r) {
      float v = acc[nt][r] + bd;
      v = fmaxf(ss * v + tt, 0.f);
      P[(rbase + r) * 134 + o] = bft(v);
    }
  }
  __syncthreads();

  // ---- conv3 MFMA (M=16, K=128) from P ----
  float4v acc2[2];
  acc2[0] = (float4v)(0.f); acc2[1] = (float4v)(0.f);
  {
    const u16* b0p = &w3b[(((size_t)(wave * 2 + 0) * 4) * 64 + lane) * 8];
    const u16* b1p = &w3b[(((size_t)(wave * 2 + 1) * 4) * 64 + lane) * 8];
#pragma unroll
    for (int ks = 0; ks < 4; ++ks) {
      short8v a = *(const short8v*)&P[nlo * 134 + ks * 32 + kgr * 8];
      short8v b0 = *(const short8v*)(b0p + ks * 512);
      short8v b1 = *(const short8v*)(b1p + ks * 512);
      acc2[0] = __builtin_amdgcn_mfma_f32_16x16x32_bf16(a, b0, acc2[0], 0, 0, 0);
      acc2[1] = __builtin_amdgcn_mfma_f32_16x16x32_bf16(a, b1, acc2[1], 0, 0, 0);
    }
  }

  // bn3 chain -> T2[o][pos] (disjoint from P region; no barrier needed)
#pragma unroll
  for (int nt = 0; nt < 2; ++nt) {
    int o = (wave * 2 + nt) * 16 + nlo;
    float sa = s3a[o], ta = t3a[o], sb = s3b[o], tb = t3b[o];
#pragma unroll
    for (int r = 0; r < 4; ++r) {
      float v = acc2[nt][r];
      v = fmaxf(sa * v + ta, 0.f);
      v = sb * v + tb;
      T2[o * 17 + rbase + r] = v;
    }
  }
  __syncthreads();

  // ---- transpose + ident + relu -> out NCHW fp32 ----
  {
    int o = tid >> 1, half = tid & 1;
    size_t g = ((size_t)((b * 128 + o) * 128 + h)) * 128 + wq * 16 + half * 8;
    const float* trow = &T2[o * 17 + half * 8];
    uint4 iv = *(const uint4*)&identb[g];
    u32 iw[4] = {iv.x, iv.y, iv.z, iv.w};
    float4 ov[2];
#pragma unroll
    for (int q = 0; q < 2; ++q) {
      float r0 = trow[q * 4 + 0] + bflo(iw[q * 2]);
      float r1 = trow[q * 4 + 1] + bfhi(iw[q * 2]);
      float r2 = trow[q * 4 + 2] + bflo(iw[q * 2 + 1]);
      float r3 = trow[q * 4 + 3] + bfhi(iw[q * 2 + 1]);
      ov[q] = make_float4(fmaxf(r0, 0.f), fmaxf(r1, 0.f), fmaxf(r2, 0.f), fmaxf(r3, 0.f));
    }
    *(float4*)&out[g] = ov[0];
    *(float4*)&out[g + 4] = ov[1];
  }
}

// ---------------------------------------------------------------------------
extern "C" void kernel_launch(void* const* d_in, const int* in_sizes, int n_in,
                              void* d_out, int out_size, void* d_ws, size_t ws_size,
                              hipStream_t stream) {
  const float* x     = (const float*)d_in[0];
  const float* w1    = (const float*)d_in[1];
  const float* s1a   = (const float*)d_in[2];
  const float* t1a   = (const float*)d_in[3];
  const float* s1b   = (const float*)d_in[4];
  const float* t1b   = (const float*)d_in[5];
  const float* w_off = (const float*)d_in[6];
  const float* b_off = (const float*)d_in[7];
  const float* w_dc  = (const float*)d_in[8];
  const float* b_dc  = (const float*)d_in[9];
  const float* s2    = (const float*)d_in[10];
  const float* t2    = (const float*)d_in[11];
  const float* w3    = (const float*)d_in[12];
  const float* s3a   = (const float*)d_in[13];
  const float* t3a   = (const float*)d_in[14];
  const float* s3b   = (const float*)d_in[15];
  const float* t3b   = (const float*)d_in[16];
  const float* w_ds  = (const float*)d_in[17];
  const float* b_ds  = (const float*)d_in[18];
  const float* sd    = (const float*)d_in[19];
  const float* td    = (const float*)d_in[20];

  char* ws = (char*)d_ws;
  u16* wTb    = (u16*)(ws + 0);            //    294,912 B
  u16* wB1    = (u16*)(ws + 294912);       //    131,072 B
  u16* w3b    = (u16*)(ws + 425984);       //     32,768 B
  u16* woffb  = (u16*)(ws + 458752);       //     73,728 B
  u16* out1   = (u16*)(ws + 532480);       // 16,777,216 B  NHWC bf16
  u16* identb = (u16*)(ws + 17309696);     // 16,777,216 B  NCHW bf16

  k_init  <<<1040, 256, 0, stream>>>(w_dc, w1, w_ds, w3, w_off, wTb, wB1, w3b, woffb);
  k_fused1<<<dim3(4, 128, 4), 256, 0, stream>>>(x, wB1, s1a, t1a, s1b, t1b, b_ds, sd, td, out1, identb);
  k_dcn   <<<dim3(8, 128, 4), 256, 0, stream>>>(out1, wTb, w3b, woffb, b_off, b_dc, s2, t2,
                                                s3a, t3a, s3b, t3b, identb, (float*)d_out);
}